// Round 6
// baseline (585.875 us; speedup 1.0000x reference)
//
#include <hip/hip_runtime.h>

// VectorQuantizer: B=16,T=8192,D=64,K=1024
// out = [quantized 131072x64 f32][indices 131072 as f32]
// Round 6: hi*hi-only MFMA (3x less MFMA, 2x less W L1 traffic), exact-fp32
// ballot rescan threshold widened 2e-3 -> 0.2 to absorb dropped cross terms.
#define MTOK  131072
#define DIMD  64
#define KCODE 1024
#define TPB   128        // tokens per block = 4 waves x 32 tokens

typedef __bf16 bf16x8 __attribute__((ext_vector_type(8)));
typedef float  f32x4  __attribute__((ext_vector_type(4)));

__device__ __forceinline__ f32x4 mfma16(bf16x8 a, bf16x8 b, f32x4 c) {
    return __builtin_amdgcn_mfma_f32_16x16x32_bf16(a, b, c, 0, 0, 0);
}

// ---- prep: pack W_hi into MFMA-fragment order + e2 tables ----
// wpk element offset = cb*1024 + win*512 + lane*8   (hi-only, compact)
// win: 0 = d0-31, 1 = d32-63 ; lane=(q,m): frag = bf16(w[cb*16+m][win*32+q*8 ..+8])
__global__ __launch_bounds__(256) void prep_kernel(
    const float* __restrict__ w, __bf16* __restrict__ wpk,
    float* __restrict__ e2n, float* __restrict__ e2) {
    int cb  = blockIdx.x;            // 0..63
    int tid = threadIdx.x;
    int win = tid >> 6, lane = tid & 63;
    int q = lane >> 4, m = lane & 15;
    if (win < 2) {
        int k = cb * 16 + m;
        int d0 = win * 32 + q * 8;
        const float* src = w + (size_t)k * DIMD + d0;
        float4 v0 = *(const float4*)(src);
        float4 v1 = *(const float4*)(src + 4);
        float f[8] = {v0.x, v0.y, v0.z, v0.w, v1.x, v1.y, v1.z, v1.w};
        bf16x8 o;
#pragma unroll
        for (int j = 0; j < 8; ++j) o[j] = (__bf16)f[j];
        *(bf16x8*)(wpk + ((size_t)(cb * 2 + win) * 64 + lane) * 8) = o;
    }
    if (tid < 16) {   // e2 in exact round-1 fma order (matches np argmin, absmax=0)
        int k2 = cb * 16 + tid;
        const float4* row = (const float4*)(w + (size_t)k2 * DIMD);
        float s = 0.f;
#pragma unroll
        for (int i = 0; i < 16; ++i) {
            float4 v = row[i];
            s = fmaf(v.x, v.x, s); s = fmaf(v.y, v.y, s);
            s = fmaf(v.z, v.z, s); s = fmaf(v.w, v.w, s);
        }
        e2[k2]  = s;
        e2n[k2] = -0.5f * s;
    }
}

__global__ __launch_bounds__(256, 4) void vq_main(
    const float* __restrict__ x, const float* __restrict__ wfull,
    const __bf16* __restrict__ wpk, const float* __restrict__ e2n_g,
    const float* __restrict__ e2_g, float* __restrict__ out) {

    const int tid  = threadIdx.x;
    const int blk  = blockIdx.x;
    const int lane = tid & 63;
    const int wv   = tid >> 6;      // wave -> tokens wv*32..+32
    const int q    = lane >> 4;
    const int m    = lane & 15;
    const size_t tok0 = (size_t)blk * TPB + wv * 32;   // wave's first token

    // ---- x_hi fragments straight from global ----
    bf16x8 bx[2][2];
#pragma unroll
    for (int tg = 0; tg < 2; ++tg) {
        const float* xr = x + (tok0 + tg * 16 + m) * DIMD;
#pragma unroll
        for (int h = 0; h < 2; ++h) {
            float4 v0 = *(const float4*)(xr + h * 32 + q * 8);
            float4 v1 = *(const float4*)(xr + h * 32 + q * 8 + 4);
            float f[8] = {v0.x, v0.y, v0.z, v0.w, v1.x, v1.y, v1.z, v1.w};
            bf16x8 hi;
#pragma unroll
            for (int j = 0; j < 8; ++j) hi[j] = (__bf16)f[j];
            bx[tg][h] = hi;
        }
    }

    float b1[2], b2[2]; int i1[2];
#pragma unroll
    for (int tg = 0; tg < 2; ++tg) { b1[tg] = -3e38f; b2[tg] = -3e38f; i1[tg] = 0; }

    // acc = dot_hh - e2/2 (C-init); argmax(acc) == argmin(dist) up to cross-term
    // error (bounded < 0.2, handled by rescan). Tracker: top-1 (value+idx,
    // strict > => ties keep lower code) + top-2 value (med3).
    auto step = [&](bf16x8 f0, bf16x8 f1, f32x4 ee, int cbase) {
#pragma unroll
        for (int tg = 0; tg < 2; ++tg) {
            f32x4 t = mfma16(f0, bx[tg][0], ee);   // w_hi*x_hi d0-31
            t = mfma16(f1, bx[tg][1], t);          // w_hi*x_hi d32-63
#pragma unroll
            for (int r = 0; r < 4; ++r) {
                float a   = t[r];
                int idxv  = cbase + q * 4 + r;
                bool gt   = a > b1[tg];
                i1[tg] = gt ? idxv : i1[tg];
                b2[tg] = __builtin_amdgcn_fmed3f(a, b1[tg], b2[tg]);
                b1[tg] = fmaxf(a, b1[tg]);
            }
        }
    };

    // ---- main loop: 64 code-blocks, W_hi frags from L2, 2-deep reg ping-pong ----
    const __bf16* wb = wpk + lane * 8;     // lane-contiguous fragment base
    const float*  eb = e2n_g + q * 4;
    bf16x8 A0 = *(const bf16x8*)(wb + 0);
    bf16x8 A1 = *(const bf16x8*)(wb + 512);
    f32x4  EA = *(const f32x4*)(eb);

    for (int cb = 0; cb < 64; cb += 2) {
        const __bf16* pB = wb + (size_t)(cb + 1) * 1024;
        bf16x8 B0 = *(const bf16x8*)(pB + 0);
        bf16x8 B1 = *(const bf16x8*)(pB + 512);
        f32x4  EB = *(const f32x4*)(eb + (cb + 1) * 16);

        step(A0, A1, EA, cb * 16);

        if (cb + 2 < 64) {
            const __bf16* pA = wb + (size_t)(cb + 2) * 1024;
            A0 = *(const bf16x8*)(pA + 0);
            A1 = *(const bf16x8*)(pA + 512);
            EA = *(const f32x4*)(eb + (cb + 2) * 16);
        }
        step(B0, B1, EB, (cb + 1) * 16);
    }

    // ---- cross-quad merge: lanes m,m+16,m+32,m+48 hold disjoint code sets ----
    float B1f[2], B2f[2]; int I1f[2];
#pragma unroll
    for (int tg = 0; tg < 2; ++tg) {
        float B1 = b1[tg], B2 = b2[tg]; int I1 = i1[tg];
#pragma unroll
        for (int mask = 16; mask <= 32; mask <<= 1) {
            float ob1 = __shfl_xor(B1, mask);
            float ob2 = __shfl_xor(B2, mask);
            int   oi  = __shfl_xor(I1, mask);
            bool take = (ob1 > B1) || (ob1 == B1 && oi < I1);
            B2 = fmaxf(fminf(ob1, B1), fmaxf(ob2, B2));
            I1 = take ? oi : I1;
            B1 = fmaxf(ob1, B1);
        }
        B1f[tg] = B1; B2f[tg] = B2; I1f[tg] = I1;   // replicated across quads
    }

    // token t (0..31) of this wave -> its index; lanes 0..31 own token lane
    int myidx;
    {
        int src = lane & 15;
        int v0 = __shfl(I1f[0], src);
        int v1 = __shfl(I1f[1], src);
        myidx = ((lane >> 4) & 1) ? v1 : v0;
    }

    // ---- ballot-driven exact fp32 rescan of near-ties (round-1 numerics) ----
    // threshold 0.2 in dot space: 8-sigma over the dropped cross-term pair error
#pragma unroll
    for (int tg = 0; tg < 2; ++tg) {
        unsigned long long msk =
            __ballot((lane < 16) && (B1f[tg] - B2f[tg] < 0.2f));
        while (msk) {
            int mm = __ffsll((unsigned long long)msk) - 1;
            msk &= msk - 1;
            int tloc = tg * 16 + mm;              // token within this wave (0..31)
            const float4* xr = (const float4*)(x + (tok0 + tloc) * DIMD);
            float bv = 3e38f; int bi = 0;
            for (int j = 0; j < 16; ++j) {
                int k = lane * 16 + j;
                const float4* wr = (const float4*)(wfull + (size_t)k * DIMD);
                float s = 0.f;
#pragma unroll
                for (int i = 0; i < 16; ++i) {
                    float4 xv = xr[i], wv4 = wr[i];
                    s = fmaf(xv.x, wv4.x, s); s = fmaf(xv.y, wv4.y, s);
                    s = fmaf(xv.z, wv4.z, s); s = fmaf(xv.w, wv4.w, s);
                }
                float dv = fmaf(-2.f, s, e2_g[k]);
                if (dv < bv) { bv = dv; bi = k; }  // ties -> lower k
            }
#pragma unroll
            for (int mask2 = 1; mask2 <= 32; mask2 <<= 1) {
                float ov = __shfl_xor(bv, mask2);
                int   oi = __shfl_xor(bi, mask2);
                bool take = (ov < bv) || (ov == bv && oi < bi);
                bv = take ? ov : bv;
                bi = take ? oi : bi;
            }
            myidx = (lane == tloc) ? bi : myidx;
        }
    }

    // ---- outputs ----
    // indices as f32 (lanes 0..31 own tokens 0..31 of this wave)
    if (lane < 32)
        out[(size_t)MTOK * DIMD + tok0 + lane] = (float)myidx;

    // coalesced gather: per j, wave writes one contiguous 1KB segment;
    // codebook row read cooperatively (16 lanes per row, contiguous 256B)
    {
        float* obase = out + tok0 * DIMD;
#pragma unroll
        for (int j = 0; j < 8; ++j) {
            int srcl = j * 4 + (lane >> 4);        // token 0..31
            int gi   = __shfl(myidx, srcl);
            float4 v = *(const float4*)(wfull + (size_t)gi * DIMD + (lane & 15) * 4);
            *(float4*)(obase + j * 256 + lane * 4) = v;
        }
    }
}

extern "C" void kernel_launch(void* const* d_in, const int* in_sizes, int n_in,
                              void* d_out, int out_size, void* d_ws, size_t ws_size,
                              hipStream_t stream) {
    const float* x = (const float*)d_in[0];
    const float* w = (const float*)d_in[1];
    float* out = (float*)d_out;

    // ws: [wpk_hi 128K][e2n 4K][e2 4K]
    __bf16* wpk = (__bf16*)d_ws;
    float*  e2n = (float*)((char*)d_ws + 131072);
    float*  e2  = (float*)((char*)d_ws + 135168);

    prep_kernel<<<64, 256, 0, stream>>>(w, wpk, e2n, e2);
    vq_main<<<MTOK / TPB, 256, 0, stream>>>(x, w, wpk, e2n, e2, out);
}

// Round 7
// 426.811 us; speedup vs baseline: 1.3727x; 1.3727x over previous
//
#include <hip/hip_runtime.h>

// VectorQuantizer: B=16,T=8192,D=64,K=1024
// out = [quantized 131072x64 f32][indices 131072 as f32]
// Round 7: round-5 structure (3-term split-bf16 MFMA, 32 tok/wave, ballot
// rescan @2e-3, coalesced epilogue) + 4-deep register prefetch pipeline.
#define MTOK  131072
#define DIMD  64
#define KCODE 1024
#define TPB   128        // tokens per block = 4 waves x 32 tokens

typedef __bf16 bf16x8 __attribute__((ext_vector_type(8)));
typedef float  f32x4  __attribute__((ext_vector_type(4)));

__device__ __forceinline__ f32x4 mfma16(bf16x8 a, bf16x8 b, f32x4 c) {
    return __builtin_amdgcn_mfma_f32_16x16x32_bf16(a, b, c, 0, 0, 0);
}

// ---- prep: pack W into MFMA-fragment order + e2 tables ----
// wpk element offset = cb*2048 + win*512 + lane*8
// win: 0=hi d0-31, 1=hi d32-63, 2=lo d0-31, 3=lo d32-63
// lane=(q,m): frag = w[cb*16+m][(win&1)*32+q*8 ..+8]
__global__ __launch_bounds__(256) void prep_kernel(
    const float* __restrict__ w, __bf16* __restrict__ wpk,
    float* __restrict__ e2n, float* __restrict__ e2) {
    int b   = blockIdx.x;
    int tid = threadIdx.x;
    if (b < 64) {                       // pack blocks
        int cb  = b;
        int win = tid >> 6, lane = tid & 63;
        int q = lane >> 4, m = lane & 15;
        int k = cb * 16 + m;
        int d0 = (win & 1) * 32 + q * 8;
        const float* src = w + (size_t)k * DIMD + d0;
        float4 v0 = *(const float4*)(src);
        float4 v1 = *(const float4*)(src + 4);
        float f[8] = {v0.x, v0.y, v0.z, v0.w, v1.x, v1.y, v1.z, v1.w};
        bf16x8 o;
#pragma unroll
        for (int j = 0; j < 8; ++j) {
            __bf16 h = (__bf16)f[j];
            o[j] = (win < 2) ? h : (__bf16)(f[j] - (float)h);
        }
        *(bf16x8*)(wpk + ((size_t)(cb * 4 + win) * 64 + lane) * 8) = o;
    } else {                            // e2 blocks: one code per thread,
        int k2 = (b - 64) * 256 + tid;  // exact round-1 fma order (absmax=0)
        const float4* row = (const float4*)(w + (size_t)k2 * DIMD);
        float s = 0.f;
#pragma unroll
        for (int i = 0; i < 16; ++i) {
            float4 v = row[i];
            s = fmaf(v.x, v.x, s); s = fmaf(v.y, v.y, s);
            s = fmaf(v.z, v.z, s); s = fmaf(v.w, v.w, s);
        }
        e2[k2]  = s;
        e2n[k2] = -0.5f * s;
    }
}

__global__ __launch_bounds__(256, 4) void vq_main(
    const float* __restrict__ x, const float* __restrict__ wfull,
    const __bf16* __restrict__ wpk, const float* __restrict__ e2n_g,
    const float* __restrict__ e2_g, float* __restrict__ out) {

    const int tid  = threadIdx.x;
    const int blk  = blockIdx.x;
    const int lane = tid & 63;
    const int wv   = tid >> 6;      // wave -> tokens wv*32..+32
    const int q    = lane >> 4;
    const int m    = lane & 15;
    const size_t tok0 = (size_t)blk * TPB + wv * 32;   // wave's first token

    // ---- x fragments straight from global, hi/lo split in registers ----
    bf16x8 bx[2][4];
#pragma unroll
    for (int tg = 0; tg < 2; ++tg) {
        const float* xr = x + (tok0 + tg * 16 + m) * DIMD;
#pragma unroll
        for (int h = 0; h < 2; ++h) {
            float4 v0 = *(const float4*)(xr + h * 32 + q * 8);
            float4 v1 = *(const float4*)(xr + h * 32 + q * 8 + 4);
            float f[8] = {v0.x, v0.y, v0.z, v0.w, v1.x, v1.y, v1.z, v1.w};
            bf16x8 hi, lo;
#pragma unroll
            for (int j = 0; j < 8; ++j) {
                __bf16 hh = (__bf16)f[j];
                hi[j] = hh;
                lo[j] = (__bf16)(f[j] - (float)hh);
            }
            bx[tg][h]     = hi;
            bx[tg][2 + h] = lo;
        }
    }

    float b1[2], b2[2]; int i1[2];
#pragma unroll
    for (int tg = 0; tg < 2; ++tg) { b1[tg] = -3e38f; b2[tg] = -3e38f; i1[tg] = 0; }

    // acc = dot - e2/2 (C-init); argmax(acc) == argmin(dist). Tracker: top-1
    // (value+idx, strict > => ties keep lower code) + top-2 value (med3).
    auto step = [&](bf16x8 f0, bf16x8 f1, bf16x8 f2, bf16x8 f3, f32x4 ee, int cbase) {
#pragma unroll
        for (int tg = 0; tg < 2; ++tg) {
            f32x4 t = mfma16(f0, bx[tg][0], ee);   // w_hi*x_hi d0-31
            t = mfma16(f1, bx[tg][1], t);          // w_hi*x_hi d32-63
            t = mfma16(f0, bx[tg][2], t);          // w_hi*x_lo
            t = mfma16(f1, bx[tg][3], t);
            t = mfma16(f2, bx[tg][0], t);          // w_lo*x_hi
            t = mfma16(f3, bx[tg][1], t);
#pragma unroll
            for (int r = 0; r < 4; ++r) {
                float a   = t[r];
                int idxv  = cbase + q * 4 + r;
                bool gt   = a > b1[tg];
                i1[tg] = gt ? idxv : i1[tg];
                b2[tg] = __builtin_amdgcn_fmed3f(a, b1[tg], b2[tg]);
                b1[tg] = fmaxf(a, b1[tg]);
            }
        }
    };

    // ---- main loop: 64 code-blocks, W frags from L2, 4-deep reg pipeline ----
    const __bf16* wb = wpk + lane * 8;     // lane-contiguous fragment base
    const float*  eb = e2n_g + q * 4;
    bf16x8 F0[4], F1[4], F2[4], F3[4];
    f32x4  E[4];
#pragma unroll
    for (int p = 0; p < 4; ++p) {
        const __bf16* pp = wb + (size_t)p * 2048;
        F0[p] = *(const bf16x8*)(pp + 0);
        F1[p] = *(const bf16x8*)(pp + 512);
        F2[p] = *(const bf16x8*)(pp + 1024);
        F3[p] = *(const bf16x8*)(pp + 1536);
        E[p]  = *(const f32x4*)(eb + p * 16);
    }
    for (int cb = 0; cb < 64; cb += 4) {
#pragma unroll
        for (int p = 0; p < 4; ++p) {
            bf16x8 a0 = F0[p], a1 = F1[p], a2 = F2[p], a3 = F3[p];
            f32x4  ee = E[p];
            int nx = cb + 4 + p;
            if (nx < 64) {               // refill slot p (4 cb in flight)
                const __bf16* pp = wb + (size_t)nx * 2048;
                F0[p] = *(const bf16x8*)(pp + 0);
                F1[p] = *(const bf16x8*)(pp + 512);
                F2[p] = *(const bf16x8*)(pp + 1024);
                F3[p] = *(const bf16x8*)(pp + 1536);
                E[p]  = *(const f32x4*)(eb + nx * 16);
            }
            step(a0, a1, a2, a3, ee, (cb + p) * 16);
        }
    }

    // ---- cross-quad merge: lanes m,m+16,m+32,m+48 hold disjoint code sets ----
    float B1f[2], B2f[2]; int I1f[2];
#pragma unroll
    for (int tg = 0; tg < 2; ++tg) {
        float B1 = b1[tg], B2 = b2[tg]; int I1 = i1[tg];
#pragma unroll
        for (int mask = 16; mask <= 32; mask <<= 1) {
            float ob1 = __shfl_xor(B1, mask);
            float ob2 = __shfl_xor(B2, mask);
            int   oi  = __shfl_xor(I1, mask);
            bool take = (ob1 > B1) || (ob1 == B1 && oi < I1);
            B2 = fmaxf(fminf(ob1, B1), fmaxf(ob2, B2));
            I1 = take ? oi : I1;
            B1 = fmaxf(ob1, B1);
        }
        B1f[tg] = B1; B2f[tg] = B2; I1f[tg] = I1;   // replicated across quads
    }

    // token t (0..31) of this wave -> its index; lanes 0..31 own token lane
    int myidx;
    {
        int src = lane & 15;
        int v0 = __shfl(I1f[0], src);
        int v1 = __shfl(I1f[1], src);
        myidx = ((lane >> 4) & 1) ? v1 : v0;
    }

    // ---- ballot-driven exact fp32 rescan of near-ties (round-1 numerics) ----
#pragma unroll
    for (int tg = 0; tg < 2; ++tg) {
        unsigned long long msk =
            __ballot((lane < 16) && (B1f[tg] - B2f[tg] < 2e-3f));
        while (msk) {
            int mm = __ffsll((unsigned long long)msk) - 1;
            msk &= msk - 1;
            int tloc = tg * 16 + mm;              // token within this wave (0..31)
            const float4* xr = (const float4*)(x + (tok0 + tloc) * DIMD);
            float bv = 3e38f; int bi = 0;
            for (int j = 0; j < 16; ++j) {
                int k = lane * 16 + j;
                const float4* wr = (const float4*)(wfull + (size_t)k * DIMD);
                float s = 0.f;
#pragma unroll
                for (int i = 0; i < 16; ++i) {
                    float4 xv = xr[i], wv4 = wr[i];
                    s = fmaf(xv.x, wv4.x, s); s = fmaf(xv.y, wv4.y, s);
                    s = fmaf(xv.z, wv4.z, s); s = fmaf(xv.w, wv4.w, s);
                }
                float dv = fmaf(-2.f, s, e2_g[k]);
                if (dv < bv) { bv = dv; bi = k; }  // ties -> lower k
            }
#pragma unroll
            for (int mask2 = 1; mask2 <= 32; mask2 <<= 1) {
                float ov = __shfl_xor(bv, mask2);
                int   oi = __shfl_xor(bi, mask2);
                bool take = (ov < bv) || (ov == bv && oi < bi);
                bv = take ? ov : bv;
                bi = take ? oi : bi;
            }
            myidx = (lane == tloc) ? bi : myidx;
        }
    }

    // ---- outputs ----
    // indices as f32 (lanes 0..31 own tokens 0..31 of this wave)
    if (lane < 32)
        out[(size_t)MTOK * DIMD + tok0 + lane] = (float)myidx;

    // coalesced gather: per j, wave writes one contiguous 1KB segment;
    // codebook row read cooperatively (16 lanes per row, contiguous 256B)
    {
        float* obase = out + tok0 * DIMD;
#pragma unroll
        for (int j = 0; j < 8; ++j) {
            int srcl = j * 4 + (lane >> 4);        // token 0..31
            int gi   = __shfl(myidx, srcl);
            float4 v = *(const float4*)(wfull + (size_t)gi * DIMD + (lane & 15) * 4);
            *(float4*)(obase + j * 256 + lane * 4) = v;
        }
    }
}

extern "C" void kernel_launch(void* const* d_in, const int* in_sizes, int n_in,
                              void* d_out, int out_size, void* d_ws, size_t ws_size,
                              hipStream_t stream) {
    const float* x = (const float*)d_in[0];
    const float* w = (const float*)d_in[1];
    float* out = (float*)d_out;

    // ws: [wpk 256K][e2n 4K][e2 4K]
    __bf16* wpk = (__bf16*)d_ws;
    float*  e2n = (float*)((char*)d_ws + 262144);
    float*  e2  = (float*)((char*)d_ws + 266240);

    prep_kernel<<<68, 256, 0, stream>>>(w, wpk, e2n, e2);
    vq_main<<<MTOK / TPB, 256, 0, stream>>>(x, w, wpk, e2n, e2, out);
}

// Round 8
// 145.064 us; speedup vs baseline: 4.0387x; 2.9422x over previous
//
#include <hip/hip_runtime.h>

// VectorQuantizer: B=16,T=8192,D=64,K=1024
// out = [quantized 131072x64 f32][indices 131072 as f32]
// Round 8: r5 math + LDS-shared W. 4 waves/block share each 16KB W chunk
// (L1 traffic /4), frag reads = ds_read_b128 lane*16+imm (no addr VALU),
// 36KB LDS -> 4 independent blocks/CU, 1 barrier/chunk, g2l prefetch 1 ahead.
#define MTOK  131072
#define DIMD  64
#define KCODE 1024
#define TPB   128        // tokens per block = 4 waves x 32 tokens

typedef __bf16 bf16x8 __attribute__((ext_vector_type(8)));
typedef float  f32x4  __attribute__((ext_vector_type(4)));

__device__ __forceinline__ f32x4 mfma16(bf16x8 a, bf16x8 b, f32x4 c) {
    return __builtin_amdgcn_mfma_f32_16x16x32_bf16(a, b, c, 0, 0, 0);
}

// async global->LDS, 16B/lane; LDS dest = wave-uniform base + lane*16
__device__ __forceinline__ void g2l16(const void* g, void* l) {
    __builtin_amdgcn_global_load_lds(
        (const __attribute__((address_space(1))) unsigned int*)g,
        (__attribute__((address_space(3))) unsigned int*)l, 16, 0, 0);
}

// ---- prep: pack W into MFMA-fragment order + e2 tables (r5-verified) ----
// wpk element offset = cb*2048 + win*512 + lane*8
// win: 0=hi d0-31, 1=hi d32-63, 2=lo d0-31, 3=lo d32-63
// lane=(q,m): frag = w[cb*16+m][(win&1)*32+q*8 ..+8]
__global__ __launch_bounds__(256) void prep_kernel(
    const float* __restrict__ w, __bf16* __restrict__ wpk,
    float* __restrict__ e2n, float* __restrict__ e2) {
    int b   = blockIdx.x;
    int tid = threadIdx.x;
    if (b < 64) {                       // pack blocks
        int cb  = b;
        int win = tid >> 6, lane = tid & 63;
        int q = lane >> 4, m = lane & 15;
        int k = cb * 16 + m;
        int d0 = (win & 1) * 32 + q * 8;
        const float* src = w + (size_t)k * DIMD + d0;
        float4 v0 = *(const float4*)(src);
        float4 v1 = *(const float4*)(src + 4);
        float f[8] = {v0.x, v0.y, v0.z, v0.w, v1.x, v1.y, v1.z, v1.w};
        bf16x8 o;
#pragma unroll
        for (int j = 0; j < 8; ++j) {
            __bf16 h = (__bf16)f[j];
            o[j] = (win < 2) ? h : (__bf16)(f[j] - (float)h);
        }
        *(bf16x8*)(wpk + ((size_t)(cb * 4 + win) * 64 + lane) * 8) = o;
    } else {                            // e2: one code/thread, exact r1 fma order
        int k2 = (b - 64) * 256 + tid;
        const float4* row = (const float4*)(w + (size_t)k2 * DIMD);
        float s = 0.f;
#pragma unroll
        for (int i = 0; i < 16; ++i) {
            float4 v = row[i];
            s = fmaf(v.x, v.x, s); s = fmaf(v.y, v.y, s);
            s = fmaf(v.z, v.z, s); s = fmaf(v.w, v.w, s);
        }
        e2[k2]  = s;
        e2n[k2] = -0.5f * s;
    }
}

__global__ __launch_bounds__(256, 4) void vq_main(
    const float* __restrict__ x, const float* __restrict__ wfull,
    const __bf16* __restrict__ wpk, const float* __restrict__ e2n_g,
    const float* __restrict__ e2_g, float* __restrict__ out) {

    // 2 x 16KB W chunk double-buffer + 4KB e2 = 36KB -> 4 blocks/CU
    __shared__ __align__(16) __bf16 ldsW[2][8192];
    __shared__ __align__(16) float  ldsE[KCODE];

    const int tid  = threadIdx.x;
    const int blk  = blockIdx.x;
    const int lane = tid & 63;
    const int wv   = tid >> 6;      // wave -> tokens wv*32..+32
    const int q    = lane >> 4;
    const int m    = lane & 15;
    const size_t tok0 = (size_t)blk * TPB + wv * 32;   // wave's first token

    // ---- issue async stage: chunk 0 (16KB) + e2 table (4KB) ----
    {
        const char* gw = (const char*)wpk + (size_t)wv * 4096 + (size_t)lane * 16;
        char* lw = (char*)&ldsW[0][0] + wv * 4096 + lane * 16;
#pragma unroll
        for (int j = 0; j < 4; ++j)
            g2l16(gw + j * 1024, lw + j * 1024);
        g2l16((const char*)e2n_g + (size_t)wv * 1024 + lane * 16,
              (char*)ldsE + wv * 1024 + lane * 16);
    }

    // ---- x fragments straight from global, hi/lo split in registers ----
    bf16x8 bx[2][4];
#pragma unroll
    for (int tg = 0; tg < 2; ++tg) {
        const float* xr = x + (tok0 + tg * 16 + m) * DIMD;
#pragma unroll
        for (int h = 0; h < 2; ++h) {
            float4 v0 = *(const float4*)(xr + h * 32 + q * 8);
            float4 v1 = *(const float4*)(xr + h * 32 + q * 8 + 4);
            float f[8] = {v0.x, v0.y, v0.z, v0.w, v1.x, v1.y, v1.z, v1.w};
            bf16x8 hi, lo;
#pragma unroll
            for (int j = 0; j < 8; ++j) {
                __bf16 hh = (__bf16)f[j];
                hi[j] = hh;
                lo[j] = (__bf16)(f[j] - (float)hh);
            }
            bx[tg][h]     = hi;
            bx[tg][2 + h] = lo;
        }
    }

    float b1[2], b2[2]; int i1[2];
#pragma unroll
    for (int tg = 0; tg < 2; ++tg) { b1[tg] = -3e38f; b2[tg] = -3e38f; i1[tg] = 0; }

    // acc = dot - e2/2 (C-init); argmax(acc) == argmin(dist). Tracker: top-1
    // (value+idx, strict > => ties keep lower code) + top-2 value (med3).
    auto step = [&](bf16x8 f0, bf16x8 f1, bf16x8 f2, bf16x8 f3, f32x4 ee, int cbase) {
#pragma unroll
        for (int tg = 0; tg < 2; ++tg) {
            f32x4 t = mfma16(f0, bx[tg][0], ee);   // w_hi*x_hi d0-31
            t = mfma16(f1, bx[tg][1], t);          // w_hi*x_hi d32-63
            t = mfma16(f0, bx[tg][2], t);          // w_hi*x_lo
            t = mfma16(f1, bx[tg][3], t);
            t = mfma16(f2, bx[tg][0], t);          // w_lo*x_hi
            t = mfma16(f3, bx[tg][1], t);
#pragma unroll
            for (int r = 0; r < 4; ++r) {
                float a   = t[r];
                int idxv  = cbase + q * 4 + r;
                bool gt   = a > b1[tg];
                i1[tg] = gt ? idxv : i1[tg];
                b2[tg] = __builtin_amdgcn_fmed3f(a, b1[tg], b2[tg]);
                b1[tg] = fmaxf(a, b1[tg]);
            }
        }
    };

    __syncthreads();   // chunk 0 + e2 resident (barrier drains vmcnt)

    // ---- main loop: 16 chunks x 64 codes; prefetch next chunk under compute ----
    for (int c = 0; c < 16; ++c) {
        if (c + 1 < 16) {
            const char* gw = (const char*)wpk + (size_t)(c + 1) * 16384
                           + (size_t)wv * 4096 + (size_t)lane * 16;
            char* lw = (char*)&ldsW[(c + 1) & 1][0] + wv * 4096 + lane * 16;
#pragma unroll
            for (int j = 0; j < 4; ++j)
                g2l16(gw + j * 1024, lw + j * 1024);
        }
        const __bf16* wb = &ldsW[c & 1][0] + lane * 8;   // frag base; rest is imm
#pragma unroll
        for (int cbl = 0; cbl < 4; ++cbl) {
            bf16x8 a0 = *(const bf16x8*)(wb + cbl * 2048 + 0);
            bf16x8 a1 = *(const bf16x8*)(wb + cbl * 2048 + 512);
            bf16x8 a2 = *(const bf16x8*)(wb + cbl * 2048 + 1024);
            bf16x8 a3 = *(const bf16x8*)(wb + cbl * 2048 + 1536);
            f32x4  ee = *(const f32x4*)&ldsE[c * 64 + cbl * 16 + q * 4];
            step(a0, a1, a2, a3, ee, (c * 4 + cbl) * 16);
        }
        __syncthreads();   // all waves done with buf c&1; prefetch c+1 landed
    }

    // ---- cross-quad merge: lanes m,m+16,m+32,m+48 hold disjoint code sets ----
    float B1f[2], B2f[2]; int I1f[2];
#pragma unroll
    for (int tg = 0; tg < 2; ++tg) {
        float B1 = b1[tg], B2 = b2[tg]; int I1 = i1[tg];
#pragma unroll
        for (int mask = 16; mask <= 32; mask <<= 1) {
            float ob1 = __shfl_xor(B1, mask);
            float ob2 = __shfl_xor(B2, mask);
            int   oi  = __shfl_xor(I1, mask);
            bool take = (ob1 > B1) || (ob1 == B1 && oi < I1);
            B2 = fmaxf(fminf(ob1, B1), fmaxf(ob2, B2));
            I1 = take ? oi : I1;
            B1 = fmaxf(ob1, B1);
        }
        B1f[tg] = B1; B2f[tg] = B2; I1f[tg] = I1;   // replicated across quads
    }

    // token t (0..31) of this wave -> its index; lanes 0..31 own token lane
    int myidx;
    {
        int src = lane & 15;
        int v0 = __shfl(I1f[0], src);
        int v1 = __shfl(I1f[1], src);
        myidx = ((lane >> 4) & 1) ? v1 : v0;
    }

    // ---- ballot-driven exact fp32 rescan of near-ties (round-1 numerics) ----
#pragma unroll
    for (int tg = 0; tg < 2; ++tg) {
        unsigned long long msk =
            __ballot((lane < 16) && (B1f[tg] - B2f[tg] < 2e-3f));
        while (msk) {
            int mm = __ffsll((unsigned long long)msk) - 1;
            msk &= msk - 1;
            int tloc = tg * 16 + mm;              // token within this wave (0..31)
            const float4* xr = (const float4*)(x + (tok0 + tloc) * DIMD);
            float bv = 3e38f; int bi = 0;
            for (int j = 0; j < 16; ++j) {
                int k = lane * 16 + j;
                const float4* wr = (const float4*)(wfull + (size_t)k * DIMD);
                float s = 0.f;
#pragma unroll
                for (int i = 0; i < 16; ++i) {
                    float4 xv = xr[i], wv4 = wr[i];
                    s = fmaf(xv.x, wv4.x, s); s = fmaf(xv.y, wv4.y, s);
                    s = fmaf(xv.z, wv4.z, s); s = fmaf(xv.w, wv4.w, s);
                }
                float dv = fmaf(-2.f, s, e2_g[k]);
                if (dv < bv) { bv = dv; bi = k; }  // ties -> lower k
            }
#pragma unroll
            for (int mask2 = 1; mask2 <= 32; mask2 <<= 1) {
                float ov = __shfl_xor(bv, mask2);
                int   oi = __shfl_xor(bi, mask2);
                bool take = (ov < bv) || (ov == bv && oi < bi);
                bv = take ? ov : bv;
                bi = take ? oi : bi;
            }
            myidx = (lane == tloc) ? bi : myidx;
        }
    }

    // ---- outputs ----
    // indices as f32 (lanes 0..31 own tokens 0..31 of this wave)
    if (lane < 32)
        out[(size_t)MTOK * DIMD + tok0 + lane] = (float)myidx;

    // coalesced gather: per j, wave writes one contiguous 1KB segment;
    // codebook row read cooperatively (16 lanes per row, contiguous 256B)
    {
        float* obase = out + tok0 * DIMD;
#pragma unroll
        for (int j = 0; j < 8; ++j) {
            int srcl = j * 4 + (lane >> 4);        // token 0..31
            int gi   = __shfl(myidx, srcl);
            float4 v = *(const float4*)(wfull + (size_t)gi * DIMD + (lane & 15) * 4);
            *(float4*)(obase + j * 256 + lane * 4) = v;
        }
    }
}

extern "C" void kernel_launch(void* const* d_in, const int* in_sizes, int n_in,
                              void* d_out, int out_size, void* d_ws, size_t ws_size,
                              hipStream_t stream) {
    const float* x = (const float*)d_in[0];
    const float* w = (const float*)d_in[1];
    float* out = (float*)d_out;

    // ws: [wpk 256K][e2n 4K][e2 4K]
    __bf16* wpk = (__bf16*)d_ws;
    float*  e2n = (float*)((char*)d_ws + 262144);
    float*  e2  = (float*)((char*)d_ws + 266240);

    prep_kernel<<<68, 256, 0, stream>>>(w, wpk, e2n, e2);
    vq_main<<<MTOK / TPB, 256, 0, stream>>>(x, w, wpk, e2n, e2, out);
}